// Round 25
// baseline (113.934 us; speedup 1.0000x reference)
//
#include <hip/hip_runtime.h>
#include <hip/hip_bf16.h>

#define NROWS 12288
#define DDIM  128
#define NT    96      // 12288/128 tiles per dimension
#define CHUNK 10      // j-tiles per block (one band per block)
#define NBLK  510     // sum over bi of ceil((96-bi)/10) -> single round, ~2 blocks/CU

typedef __bf16 bf16x8 __attribute__((ext_vector_type(8)));
typedef float  f32x4  __attribute__((ext_vector_type(4)));

// async global->LDS, 16B per lane; LDS dst is wave-uniform base + lane*16
#define GLD_LDS(g, l) __builtin_amdgcn_global_load_lds(                      \
    (const __attribute__((address_space(1))) void*)(g),                      \
    (__attribute__((address_space(3))) void*)(l), 16, 0, 0)

__device__ __forceinline__ unsigned short f2bf(float f) {
    union { float f; unsigned u; } a; a.f = f;
    unsigned r = a.u + 0x7fffu + ((a.u >> 16) & 1u);   // RNE to bf16
    return (unsigned short)(r >> 16);
}

// Convert f32 -> bf16 AND permute into fragment-major layout:
// for 16-row block rb, k-chunk ks (16B units c = ks*4+q), lane l = m16 + 16q:
//   xbT ushort offset ((rb*4 + ks)*64 + l) * 8  holds row rb*16+m16, bytes [c*16, c*16+16)
// -> every MFMA fragment load is ONE coalesced 1KB global_load_dwordx4, and one
// band's A (128 rows) is a CONTIGUOUS 32KB region (bi*32KB).
__global__ void convert_kernel(const float* __restrict__ x, unsigned short* __restrict__ xbT,
                               float* __restrict__ out) {
    int gid = blockIdx.x * 256 + threadIdx.x;    // 196608 threads, one 16B chunk each
    int e = gid << 3;
    float4 v0 = *(const float4*)(x + e);
    float4 v1 = *(const float4*)(x + e + 4);
    uint4 o;
    o.x = (unsigned)f2bf(v0.x) | ((unsigned)f2bf(v0.y) << 16);
    o.y = (unsigned)f2bf(v0.z) | ((unsigned)f2bf(v0.w) << 16);
    o.z = (unsigned)f2bf(v1.x) | ((unsigned)f2bf(v1.y) << 16);
    o.w = (unsigned)f2bf(v1.z) | ((unsigned)f2bf(v1.w) << 16);
    int r = gid >> 4;          // row
    int c = gid & 15;          // 16B chunk within row
    int off = (((r >> 4) * 4 + (c >> 2)) * 64 + (c & 3) * 16 + (r & 15)) * 8;
    *(uint4*)(xbT + off) = o;
    if (gid == 0) out[0] = 0.f;
}

// ZERO-global-atomic GEMM+exp+rowsum. One band per block (chunked decode), so
// every tile (bi,jt), every (band,chunk,wc) has a unique owner -> partials land
// via PLAIN coalesced stores:
//   rowpart[((bi*CHUNK+chunkid)*2 + wc)*128 + row]   (per-wc slot: the two wc
//     waves cover different column halves of the same rows -> MUST NOT share a
//     slot; R24's shared-slot version raced and lost half the row sums)
//   colpart[(bi*NT+jt)*128 + col]
// Compute core identical to R14 (A per-ks from LDS, B per-ks ping-pong with
// next-tile prefetch, ~84 VGPR, no spill).
// NOTE: do NOT force 4 blocks/CU (R9/R13: VGPR<=128 -> scratch spill).
__global__ __launch_bounds__(256, 2) void gemm_exp_rowsum(
    const unsigned short* __restrict__ xbT, float* __restrict__ rowpart,
    float* __restrict__ colpart)
{
    __shared__ __align__(16) unsigned short Alds[128 * DDIM];  // 32KB frag-major A band
    __shared__ float csumS[CHUNK * 128];         // 5 KB per-tile col partials

    const int tid = threadIdx.x;

    // decode blockIdx -> (band bi, chunk index within band)
    int rem = blockIdx.x, bi = 0;
    for (;;) {
        int nch = (NT - bi + CHUNK - 1) / CHUNK;
        if (rem < nch) break;
        rem -= nch; ++bi;
    }
    const int chunkid = rem;
    const int jt0 = bi + chunkid * CHUNK;
    const int ntiles = min(CHUNK, NT - jt0);

    for (int k = tid; k < CHUNK * 128; k += 256) csumS[k] = 0.f;

    const int wave = tid >> 6, lane = tid & 63;
    const int m16 = lane & 15, q = lane >> 4;
    const int wr = wave >> 1, wc = wave & 1;     // 2x2 waves, 64x64 quadrants

    // stage this band's A (contiguous 32KB at xbT + bi*16384) into LDS
    #pragma unroll
    for (int r8 = 0; r8 < 8; ++r8) {
        int ch = r8 * 256 + wave * 64;           // wave-uniform 16B-chunk base
        GLD_LDS(xbT + bi * 16384 + (ch + lane) * 8, Alds + ch * 8);
    }
    __syncthreads();   // A staged (vmcnt drained) + csumS zeroed

    // exp(s/T) == exp2(s * invT*log2e)
    const float SCALE = 20.609929155556625f;     // (1/0.07) * log2(e)

    f32x4 rp4[4];
    #pragma unroll
    for (int mi = 0; mi < 4; ++mi) rp4[mi] = (f32x4){0.f, 0.f, 0.f, 0.f};

    // 4 coalesced 1KB loads: tile jtv's B quadrant, k-chunk ks only
    #define LOAD_BKS(dst, jtv, ks) do {                                          \
        int bb = ((jtv) * 8 + wc * 4);                                           \
        _Pragma("unroll")                                                        \
        for (int ni = 0; ni < 4; ++ni)                                           \
            dst[ni] = *(const bf16x8*)(xbT + (((bb + ni) * 4 + (ks)) * 64 + lane) * 8); \
    } while (0)

    // 4 ds_read_b128 (A frags, conflict-free) + 16 MFMA for one ks
    #define MFMA_KS(ks, bfr) do {                                                \
        bf16x8 afk[4];                                                           \
        _Pragma("unroll")                                                        \
        for (int mi = 0; mi < 4; ++mi)                                           \
            afk[mi] = *(const bf16x8*)(&Alds[(((wr * 4 + mi) * 4 + (ks)) * 64 + lane) * 8]); \
        _Pragma("unroll")                                                        \
        for (int mi = 0; mi < 4; ++mi)                                           \
            _Pragma("unroll")                                                    \
            for (int ni = 0; ni < 4; ++ni)                                       \
                acc[mi][ni] = __builtin_amdgcn_mfma_f32_16x16x32_bf16(           \
                    afk[mi], bfr[ni], acc[mi][ni], 0, 0, 0);                     \
    } while (0)

    bf16x8 bf0[4], bf1[4];
    LOAD_BKS(bf0, jt0, 0);

    for (int t = 0; t < ntiles; ++t) {
        const int jt = jt0 + t;
        const bool more = (t + 1 < ntiles);

        f32x4 acc[4][4] = {};
        LOAD_BKS(bf1, jt, 1);
        MFMA_KS(0, bf0);
        LOAD_BKS(bf0, jt, 2);
        MFMA_KS(1, bf1);
        LOAD_BKS(bf1, jt, 3);
        MFMA_KS(2, bf0);
        if (more) LOAD_BKS(bf0, jt + 1, 0);      // next tile's ks0 under ks3+epilogue
        MFMA_KS(3, bf1);

        // C/D layout: col = m16, row = q*4 + r  [verified, absmax=0]
        f32x4 cp4[4];
        #pragma unroll
        for (int ni = 0; ni < 4; ++ni) cp4[ni] = (f32x4){0.f, 0.f, 0.f, 0.f};

        #pragma unroll
        for (int mi = 0; mi < 4; ++mi)
            #pragma unroll
            for (int ni = 0; ni < 4; ++ni) {
                f32x4 sv = acc[mi][ni] * SCALE;
                f32x4 ev;
                ev[0] = __builtin_amdgcn_exp2f(sv[0]);
                ev[1] = __builtin_amdgcn_exp2f(sv[1]);
                ev[2] = __builtin_amdgcn_exp2f(sv[2]);
                ev[3] = __builtin_amdgcn_exp2f(sv[3]);
                rp4[mi] += ev;                   // row partials (register, whole strip)
                cp4[ni] += ev;                   // col partials (this tile)
            }

        if (jt != bi) {                          // diagonal tile: rows only, no double count
            #pragma unroll
            for (int ni = 0; ni < 4; ++ni) {
                float s = (cp4[ni][0] + cp4[ni][1]) + (cp4[ni][2] + cp4[ni][3]);
                s += __shfl_xor(s, 16);
                s += __shfl_xor(s, 32);
                if (q == 0) atomicAdd(&csumS[t * 128 + wc * 64 + ni * 16 + m16], s);
            }
        }
    }

    // row partials: PLAIN store to this block's PER-WC slot (wc waves cover
    // different column halves of the same rows -> separate slots, summed in finalize)
    #pragma unroll
    for (int mi = 0; mi < 4; ++mi)
        #pragma unroll
        for (int r = 0; r < 4; ++r) {
            float s = rp4[mi][r];
            s += __shfl_xor(s, 1);
            s += __shfl_xor(s, 2);
            s += __shfl_xor(s, 4);
            s += __shfl_xor(s, 8);
            if (m16 == 0)
                rowpart[(((bi * CHUNK + chunkid) * 2) + wc) * 128 + wr * 64 + mi * 16 + q * 4 + r] = s;
        }

    __syncthreads();   // all csumS LDS atomics visible
    // col partials: PLAIN store to tile-unique slot colpart[bi][jt][:]
    for (int k = tid; k < ntiles * 128; k += 256) {
        int jt2 = jt0 + (k >> 7);
        if (jt2 != bi) colpart[(bi * NT + jt2) * 128 + (k & 127)] = csumS[k];
    }
    #undef LOAD_BKS
    #undef MFMA_KS
}

// Gather partials (no atomics anywhere upstream), then log + mean-reduce.
__global__ void finalize_kernel(const float* __restrict__ rowpart,
                                const float* __restrict__ colpart,
                                float* __restrict__ out) {
    __shared__ float red[4];
    int r = blockIdx.x * 256 + threadIdx.x;      // row index 0..12287
    int bj = r >> 7, c = r & 127;

    float s = 0.f;
    int nch = (NT - bj + CHUNK - 1) / CHUNK;
    for (int ch = 0; ch < nch * 2; ++ch)         // 2 wc-slots per chunk
        s += rowpart[(bj * CHUNK * 2 + ch) * 128 + c];
    for (int b2 = 0; b2 < bj; ++b2)
        s += colpart[(b2 * NT + bj) * 128 + c];

    float lg = __logf(s);
    #pragma unroll
    for (int off = 1; off < 64; off <<= 1)
        lg += __shfl_xor(lg, off);
    const int wv = threadIdx.x >> 6, ln = threadIdx.x & 63;
    if (ln == 0) red[wv] = lg;
    __syncthreads();
    if (threadIdx.x == 0)
        atomicAdd(out, (red[0] + red[1] + red[2] + red[3]) * (1.0f / (float)NROWS));
}

extern "C" void kernel_launch(void* const* d_in, const int* in_sizes, int n_in,
                              void* d_out, int out_size, void* d_ws, size_t ws_size,
                              hipStream_t stream) {
    const float* x = (const float*)d_in[0];
    float* out = (float*)d_out;

    unsigned short* xbT = (unsigned short*)d_ws;                       // 3 MB bf16, frag-major
    float* rowpart = (float*)((char*)d_ws + 3 * 1024 * 1024);          // 96*10*2*128 f32 = 960 KB
    float* colpart = rowpart + NT * CHUNK * 2 * 128;                   // 96*96*128 f32 = 4.5 MB

    convert_kernel<<<dim3((NROWS * DDIM) / (8 * 256)), dim3(256), 0, stream>>>(x, xbT, out);
    gemm_exp_rowsum<<<dim3(NBLK), dim3(256), 0, stream>>>(xbT, rowpart, colpart);
    finalize_kernel<<<dim3(NROWS / 256), dim3(256), 0, stream>>>(rowpart, colpart, out);
}

// Round 26
// 97.374 us; speedup vs baseline: 1.1701x; 1.1701x over previous
//
#include <hip/hip_runtime.h>
#include <hip/hip_bf16.h>

#define NROWS 12288
#define DDIM  128
#define NT    96      // 12288/128 tiles per dimension
#define CHUNK 10      // j-tiles per block (one band per block)
#define NBLK  510     // sum over bi of ceil((96-bi)/10) -> single round, ~2 blocks/CU

typedef __bf16 bf16x8 __attribute__((ext_vector_type(8)));
typedef float  f32x4  __attribute__((ext_vector_type(4)));

// async global->LDS, 16B per lane; LDS dst is wave-uniform base + lane*16
#define GLD_LDS(g, l) __builtin_amdgcn_global_load_lds(                      \
    (const __attribute__((address_space(1))) void*)(g),                      \
    (__attribute__((address_space(3))) void*)(l), 16, 0, 0)

__device__ __forceinline__ unsigned short f2bf(float f) {
    union { float f; unsigned u; } a; a.f = f;
    unsigned r = a.u + 0x7fffu + ((a.u >> 16) & 1u);   // RNE to bf16
    return (unsigned short)(r >> 16);
}

// Convert f32 -> bf16 AND permute into fragment-major layout:
// for 16-row block rb, k-chunk ks (16B units c = ks*4+q), lane l = m16 + 16q:
//   xbT ushort offset ((rb*4 + ks)*64 + l) * 8  holds row rb*16+m16, bytes [c*16, c*16+16)
// -> every MFMA fragment load is ONE coalesced 1KB global_load_dwordx4, and one
// band's A (128 rows) is a CONTIGUOUS 32KB region (bi*32KB).
__global__ void convert_kernel(const float* __restrict__ x, unsigned short* __restrict__ xbT,
                               float* __restrict__ out) {
    int gid = blockIdx.x * 256 + threadIdx.x;    // 196608 threads, one 16B chunk each
    int e = gid << 3;
    float4 v0 = *(const float4*)(x + e);
    float4 v1 = *(const float4*)(x + e + 4);
    uint4 o;
    o.x = (unsigned)f2bf(v0.x) | ((unsigned)f2bf(v0.y) << 16);
    o.y = (unsigned)f2bf(v0.z) | ((unsigned)f2bf(v0.w) << 16);
    o.z = (unsigned)f2bf(v1.x) | ((unsigned)f2bf(v1.y) << 16);
    o.w = (unsigned)f2bf(v1.z) | ((unsigned)f2bf(v1.w) << 16);
    int r = gid >> 4;          // row
    int c = gid & 15;          // 16B chunk within row
    int off = (((r >> 4) * 4 + (c >> 2)) * 64 + (c & 3) * 16 + (r & 15)) * 8;
    *(uint4*)(xbT + off) = o;
    if (gid == 0) out[0] = 0.f;
}

// ZERO-global-atomic GEMM+exp+rowsum. One band per block (chunked decode), so
// every tile (bi,jt), every (band,chunk,wc) has a unique owner -> partials land
// via PLAIN coalesced stores:
//   rowpart[((bi*CHUNK+chunkid)*2 + wc)*128 + row]   (per-wc slot: the two wc
//     waves cover different column halves of the same rows)
//   colpart[(bi*NT+jt)*128 + col]
// Compute core identical to R14 (A per-ks from LDS, B per-ks ping-pong with
// next-tile prefetch, ~84 VGPR, no spill).
// NOTE: do NOT force 4 blocks/CU (R9/R13: VGPR<=128 -> scratch spill).
__global__ __launch_bounds__(256, 2) void gemm_exp_rowsum(
    const unsigned short* __restrict__ xbT, float* __restrict__ rowpart,
    float* __restrict__ colpart)
{
    __shared__ __align__(16) unsigned short Alds[128 * DDIM];  // 32KB frag-major A band
    __shared__ float csumS[CHUNK * 128];         // 5 KB per-tile col partials

    const int tid = threadIdx.x;

    // decode blockIdx -> (band bi, chunk index within band)
    int rem = blockIdx.x, bi = 0;
    for (;;) {
        int nch = (NT - bi + CHUNK - 1) / CHUNK;
        if (rem < nch) break;
        rem -= nch; ++bi;
    }
    const int chunkid = rem;
    const int jt0 = bi + chunkid * CHUNK;
    const int ntiles = min(CHUNK, NT - jt0);

    for (int k = tid; k < CHUNK * 128; k += 256) csumS[k] = 0.f;

    const int wave = tid >> 6, lane = tid & 63;
    const int m16 = lane & 15, q = lane >> 4;
    const int wr = wave >> 1, wc = wave & 1;     // 2x2 waves, 64x64 quadrants

    // stage this band's A (contiguous 32KB at xbT + bi*16384) into LDS
    #pragma unroll
    for (int r8 = 0; r8 < 8; ++r8) {
        int ch = r8 * 256 + wave * 64;           // wave-uniform 16B-chunk base
        GLD_LDS(xbT + bi * 16384 + (ch + lane) * 8, Alds + ch * 8);
    }
    __syncthreads();   // A staged (vmcnt drained) + csumS zeroed

    // exp(s/T) == exp2(s * invT*log2e)
    const float SCALE = 20.609929155556625f;     // (1/0.07) * log2(e)

    f32x4 rp4[4];
    #pragma unroll
    for (int mi = 0; mi < 4; ++mi) rp4[mi] = (f32x4){0.f, 0.f, 0.f, 0.f};

    // 4 coalesced 1KB loads: tile jtv's B quadrant, k-chunk ks only
    #define LOAD_BKS(dst, jtv, ks) do {                                          \
        int bb = ((jtv) * 8 + wc * 4);                                           \
        _Pragma("unroll")                                                        \
        for (int ni = 0; ni < 4; ++ni)                                           \
            dst[ni] = *(const bf16x8*)(xbT + (((bb + ni) * 4 + (ks)) * 64 + lane) * 8); \
    } while (0)

    // 4 ds_read_b128 (A frags, conflict-free) + 16 MFMA for one ks
    #define MFMA_KS(ks, bfr) do {                                                \
        bf16x8 afk[4];                                                           \
        _Pragma("unroll")                                                        \
        for (int mi = 0; mi < 4; ++mi)                                           \
            afk[mi] = *(const bf16x8*)(&Alds[(((wr * 4 + mi) * 4 + (ks)) * 64 + lane) * 8]); \
        _Pragma("unroll")                                                        \
        for (int mi = 0; mi < 4; ++mi)                                           \
            _Pragma("unroll")                                                    \
            for (int ni = 0; ni < 4; ++ni)                                       \
                acc[mi][ni] = __builtin_amdgcn_mfma_f32_16x16x32_bf16(           \
                    afk[mi], bfr[ni], acc[mi][ni], 0, 0, 0);                     \
    } while (0)

    bf16x8 bf0[4], bf1[4];
    LOAD_BKS(bf0, jt0, 0);

    for (int t = 0; t < ntiles; ++t) {
        const int jt = jt0 + t;
        const bool more = (t + 1 < ntiles);

        f32x4 acc[4][4] = {};
        LOAD_BKS(bf1, jt, 1);
        MFMA_KS(0, bf0);
        LOAD_BKS(bf0, jt, 2);
        MFMA_KS(1, bf1);
        LOAD_BKS(bf1, jt, 3);
        MFMA_KS(2, bf0);
        if (more) LOAD_BKS(bf0, jt + 1, 0);      // next tile's ks0 under ks3+epilogue
        MFMA_KS(3, bf1);

        // C/D layout: col = m16, row = q*4 + r  [verified, absmax=0]
        f32x4 cp4[4];
        #pragma unroll
        for (int ni = 0; ni < 4; ++ni) cp4[ni] = (f32x4){0.f, 0.f, 0.f, 0.f};

        #pragma unroll
        for (int mi = 0; mi < 4; ++mi)
            #pragma unroll
            for (int ni = 0; ni < 4; ++ni) {
                f32x4 sv = acc[mi][ni] * SCALE;
                f32x4 ev;
                ev[0] = __builtin_amdgcn_exp2f(sv[0]);
                ev[1] = __builtin_amdgcn_exp2f(sv[1]);
                ev[2] = __builtin_amdgcn_exp2f(sv[2]);
                ev[3] = __builtin_amdgcn_exp2f(sv[3]);
                rp4[mi] += ev;                   // row partials (register, whole strip)
                cp4[ni] += ev;                   // col partials (this tile)
            }

        if (jt != bi) {                          // diagonal tile: rows only, no double count
            #pragma unroll
            for (int ni = 0; ni < 4; ++ni) {
                float s = (cp4[ni][0] + cp4[ni][1]) + (cp4[ni][2] + cp4[ni][3]);
                s += __shfl_xor(s, 16);
                s += __shfl_xor(s, 32);
                if (q == 0) atomicAdd(&csumS[t * 128 + wc * 64 + ni * 16 + m16], s);
            }
        }
    }

    // row partials: PLAIN store to this block's PER-WC slot
    #pragma unroll
    for (int mi = 0; mi < 4; ++mi)
        #pragma unroll
        for (int r = 0; r < 4; ++r) {
            float s = rp4[mi][r];
            s += __shfl_xor(s, 1);
            s += __shfl_xor(s, 2);
            s += __shfl_xor(s, 4);
            s += __shfl_xor(s, 8);
            if (m16 == 0)
                rowpart[(((bi * CHUNK + chunkid) * 2) + wc) * 128 + wr * 64 + mi * 16 + q * 4 + r] = s;
        }

    __syncthreads();   // all csumS LDS atomics visible
    // col partials: PLAIN store to tile-unique slot colpart[bi][jt][:]
    for (int k = tid; k < ntiles * 128; k += 256) {
        int jt2 = jt0 + (k >> 7);
        if (jt2 != bi) colpart[(bi * NT + jt2) * 128 + (k & 127)] = csumS[k];
    }
    #undef LOAD_BKS
    #undef MFMA_KS
}

// Parallel gather: 8 lanes per row (R25's 48-block serial walk was a ~20us
// latency tail). Grid = NROWS*8/256 = 384 blocks; each thread sums slots
// j = k, k+8, ... of its row (~13 loads), 3-step shfl combines lanes,
// lane k==0 takes log, wave+LDS reduce for the mean.
__global__ void finalize_kernel(const float* __restrict__ rowpart,
                                const float* __restrict__ colpart,
                                float* __restrict__ out) {
    __shared__ float red[4];
    int t = blockIdx.x * 256 + threadIdx.x;      // 98304 threads
    int r = t >> 3, k = t & 7;                   // row, slot-lane
    int bj = r >> 7, c = r & 127;

    int nch2 = 2 * ((NT - bj + CHUNK - 1) / CHUNK);
    int cnt = nch2 + bj;                         // total partial slots for this row

    float s = 0.f;
    for (int j = k; j < cnt; j += 8)
        s += (j < nch2) ? rowpart[(bj * CHUNK * 2 + j) * 128 + c]
                        : colpart[((j - nch2) * NT + bj) * 128 + c];

    // combine the 8 slot-lanes of this row
    s += __shfl_xor(s, 1);
    s += __shfl_xor(s, 2);
    s += __shfl_xor(s, 4);

    float lg = (k == 0) ? __logf(s) : 0.f;
    // sum the 8 rows in this wave (k==0 lanes are at offsets 0,8,...,56)
    lg += __shfl_xor(lg, 8);
    lg += __shfl_xor(lg, 16);
    lg += __shfl_xor(lg, 32);

    const int wv = threadIdx.x >> 6, ln = threadIdx.x & 63;
    if (ln == 0) red[wv] = lg;
    __syncthreads();
    if (threadIdx.x == 0)
        atomicAdd(out, (red[0] + red[1] + red[2] + red[3]) * (1.0f / (float)NROWS));
}

extern "C" void kernel_launch(void* const* d_in, const int* in_sizes, int n_in,
                              void* d_out, int out_size, void* d_ws, size_t ws_size,
                              hipStream_t stream) {
    const float* x = (const float*)d_in[0];
    float* out = (float*)d_out;

    unsigned short* xbT = (unsigned short*)d_ws;                       // 3 MB bf16, frag-major
    float* rowpart = (float*)((char*)d_ws + 3 * 1024 * 1024);          // 96*10*2*128 f32 = 960 KB
    float* colpart = rowpart + NT * CHUNK * 2 * 128;                   // 96*96*128 f32 = 4.5 MB

    convert_kernel<<<dim3((NROWS * DDIM) / (8 * 256)), dim3(256), 0, stream>>>(x, xbT, out);
    gemm_exp_rowsum<<<dim3(NBLK), dim3(256), 0, stream>>>(xbT, rowpart, colpart);
    finalize_kernel<<<dim3(NROWS * 8 / 256), dim3(256), 0, stream>>>(rowpart, colpart, out);
}